// Round 7
// baseline (647.235 us; speedup 1.0000x reference)
//
#include <hip/hip_runtime.h>
#include <stdint.h>

// MLP_tcnn: x(524288x64) -> [W0 64x128 relu] -> [W1..W4 128x128 relu] -> [W5 128x16] + bias
// R7: R6's register-resident kappa structure + ALL weights in LDS (persistent blocks).
//  - R6 diagnosis: A-loads from L1/L2 (~300-500cyc, dynamic) serialize at 2 waves/SIMD
//    with no spare VGPRs for deep in-flight batches -> latency-bound, MfmaUtil 17%.
//  - Weight image = 151552 B <= 160KB LDS. Stage ONCE per block via global_load_lds,
//    one barrier, then each wave runs 2 sample-tiles fully in-register, A-frags via
//    contiguous conflict-free ds_read_b128 at STATIC offsets (~120cyc, lgkmcnt-pipelined).
//  - B-frags stay lane-local via the kappa feature permutation (no LDS for activations,
//    no cross-lane, no barriers in the main loop). 512-thr blocks (8 waves), 1 block/CU
//    (LDS-capped), 512 blocks x 2 tiles/wave.

typedef __bf16 bf16x8 __attribute__((ext_vector_type(8)));
typedef float  floatx4 __attribute__((ext_vector_type(4)));

#define GAS __attribute__((address_space(1)))
#define LAS __attribute__((address_space(3)))

constexpr int NS   = 524288;        // samples
constexpr int SPW  = 64;            // samples per wave-tile
constexpr int NBLK = 512;           // blocks (8 waves each)
constexpr int TPW  = NS / (NBLK * 8 * SPW);   // = 2 tiles per wave

// weight image in 16B chunks inside d_ws, FRAG-LINEAR (frag = rb*KT + kt; 64 lanes x 16B):
// A-frag lane l, elem e = W[in = kappa(32kt+8*(l>>4)+e)][out = 16rb+(l&15)]
// L0 (K=64, kappa=identity on input): 8rb x 2kt = 16 frags; L1-4: 8 x 4 = 32; L5: 1 x 4.
constexpr int WTOT = 9472;          // total chunks = 151552 bytes

__device__ __host__ __forceinline__ int kappa(int s) {
  // s = 32*kt + 8*g + e  ->  feature 32*kt + 16*((e>>2)) + 4*g + (e&3)
  return 32 * (s >> 5) + 16 * ((s >> 2) & 1) + 4 * ((s >> 3) & 3) + (s & 3);
}

__global__ void prep_weights(const float* __restrict__ W0, const float* __restrict__ W1,
                             const float* __restrict__ W2, const float* __restrict__ W3,
                             const float* __restrict__ W4, const float* __restrict__ W5,
                             bf16x8* __restrict__ ws) {
  int gid = blockIdx.x * blockDim.x + threadIdx.x;
  if (gid >= WTOT) return;
  const float* Wsrc; int nout, kt_n, base, ident;
  if (gid < 1024)      { Wsrc = W0; nout = 128; kt_n = 2; base = 0;    ident = 1; }
  else if (gid < 3072) { Wsrc = W1; nout = 128; kt_n = 4; base = 1024; ident = 0; }
  else if (gid < 5120) { Wsrc = W2; nout = 128; kt_n = 4; base = 3072; ident = 0; }
  else if (gid < 7168) { Wsrc = W3; nout = 128; kt_n = 4; base = 5120; ident = 0; }
  else if (gid < 9216) { Wsrc = W4; nout = 128; kt_n = 4; base = 7168; ident = 0; }
  else                 { Wsrc = W5; nout = 16;  kt_n = 4; base = 9216; ident = 0; }
  int id   = gid - base;
  int lane = id & 63;
  int frag = id >> 6;
  int kt   = frag % kt_n;
  int rb   = frag / kt_n;
  int outf = rb * 16 + (lane & 15);
  int gg   = lane >> 4;
  bf16x8 v;
#pragma unroll
  for (int e = 0; e < 8; ++e) {
    int s  = 32 * kt + 8 * gg + e;           // k-slot
    int in = ident ? s : kappa(s);           // logical input feature at this slot
    v[e] = (__bf16)Wsrc[in * nout + outf];
  }
  ws[gid] = v;
}

__device__ __forceinline__ void zero_acc(floatx4 acc[8][4]) {
  floatx4 z = {0.f, 0.f, 0.f, 0.f};
#pragma unroll
  for (int ot = 0; ot < 8; ++ot)
#pragma unroll
    for (int i = 0; i < 4; ++i) acc[ot][i] = z;
}

// acc (C layout) -> B-frags for the next layer under kappa: pure lane-local relu+pack.
__device__ __forceinline__ void pack_relu(const floatx4 acc[8][4], bf16x8 B[4][4]) {
#pragma unroll
  for (int kt = 0; kt < 4; ++kt)
#pragma unroll
    for (int i = 0; i < 4; ++i) {
      floatx4 u = acc[2 * kt][i], v = acc[2 * kt + 1][i];
      bf16x8 b;
      b[0] = (__bf16)fmaxf(u[0], 0.f); b[1] = (__bf16)fmaxf(u[1], 0.f);
      b[2] = (__bf16)fmaxf(u[2], 0.f); b[3] = (__bf16)fmaxf(u[3], 0.f);
      b[4] = (__bf16)fmaxf(v[0], 0.f); b[5] = (__bf16)fmaxf(v[1], 0.f);
      b[6] = (__bf16)fmaxf(v[2], 0.f); b[7] = (__bf16)fmaxf(v[3], 0.f);
      B[kt][i] = b;
    }
}

__global__ void __launch_bounds__(512, 2) mlp_kernel(const float* __restrict__ x,
                                                     const float* __restrict__ bias,
                                                     const bf16x8* __restrict__ wimg,
                                                     float* __restrict__ out) {
  __shared__ bf16x8 Wlds[WTOT];        // 151552 B: entire frag-linear weight image

  const int t    = threadIdx.x;
  const int lane = t & 63;
  const int w    = t >> 6;             // wave 0..7
  const int l15  = lane & 15;
  const int g    = lane >> 4;

  // ---- stage all weights -> LDS (once). Identity copy: per-wave 64-chunk slabs. ----
#pragma unroll
  for (int r = 0; r < 19; ++r) {
    int base = r * 512 + w * 64;
    if (base < WTOT)
      __builtin_amdgcn_global_load_lds((const GAS void*)(wimg + base + lane),
                                       (LAS void*)(Wlds + base), 16, 0, 0);
  }
  __syncthreads();   // drains vmcnt; only barrier in the kernel

  const int wid = blockIdx.x * 8 + w;  // global wave id 0..4095

  for (int k = 0; k < TPW; ++k) {
    const size_t sbase = ((size_t)wid * TPW + k) * SPW;   // this tile's first sample

    bf16x8  B[4][4];     // B-frags: [kt][i], sample 16i+l15, k-slots 8g..8g+7 of chunk kt
    floatx4 acc[8][4];   // C: out-feature 16ot+4g+j, sample 16i+l15

    // ---- load x tile directly into B-frag layout (natural feature order) ----
    const float* xw = x + sbase * 64;
#pragma unroll
    for (int kt = 0; kt < 2; ++kt)
#pragma unroll
      for (int i = 0; i < 4; ++i) {
        const floatx4* p = (const floatx4*)(xw + (16 * i + l15) * 64 + 32 * kt + 8 * g);
        floatx4 lo = p[0], hi = p[1];
        bf16x8 v;
        v[0] = (__bf16)lo[0]; v[1] = (__bf16)lo[1]; v[2] = (__bf16)lo[2]; v[3] = (__bf16)lo[3];
        v[4] = (__bf16)hi[0]; v[5] = (__bf16)hi[1]; v[6] = (__bf16)hi[2]; v[7] = (__bf16)hi[3];
        B[kt][i] = v;
      }

    // ---- layer 0: K=64 ----
    zero_acc(acc);
#pragma unroll
    for (int kt = 0; kt < 2; ++kt)
#pragma unroll
      for (int ot = 0; ot < 8; ++ot) {
        bf16x8 a = Wlds[(ot * 2 + kt) * 64 + lane];       // ds_read_b128, static offset
#pragma unroll
        for (int i = 0; i < 4; ++i)
          acc[ot][i] = __builtin_amdgcn_mfma_f32_16x16x32_bf16(a, B[kt][i], acc[ot][i], 0, 0, 0);
      }

    // ---- layers 1..4: K=128, fully in-register ----
    constexpr int WOFFH[4] = {1024, 3072, 5120, 7168};
#pragma unroll
    for (int l = 0; l < 4; ++l) {
      pack_relu(acc, B);
      zero_acc(acc);
      const bf16x8* Wl = Wlds + WOFFH[l];
#pragma unroll
      for (int kt = 0; kt < 4; ++kt)
#pragma unroll
        for (int ot = 0; ot < 8; ++ot) {
          bf16x8 a = Wl[(ot * 4 + kt) * 64 + lane];
#pragma unroll
          for (int i = 0; i < 4; ++i)
            acc[ot][i] = __builtin_amdgcn_mfma_f32_16x16x32_bf16(a, B[kt][i], acc[ot][i], 0, 0, 0);
        }
    }

    // ---- layer 5: M=16, K=128, no relu, + bias, fp32 store ----
    pack_relu(acc, B);
    floatx4 o[4];
    {
      floatx4 z = {0.f, 0.f, 0.f, 0.f};
      o[0] = z; o[1] = z; o[2] = z; o[3] = z;
    }
#pragma unroll
    for (int kt = 0; kt < 4; ++kt) {
      bf16x8 a = Wlds[9216 + kt * 64 + lane];
#pragma unroll
      for (int i = 0; i < 4; ++i)
        o[i] = __builtin_amdgcn_mfma_f32_16x16x32_bf16(a, B[kt][i], o[i], 0, 0, 0);
    }
    floatx4 bv = *(const floatx4*)(bias + 4 * g);
    floatx4* outv = (floatx4*)out;
#pragma unroll
    for (int i = 0; i < 4; ++i) {
      size_t s = sbase + 16 * i + l15;
      outv[s * 4 + g] = o[i] + bv;    // coalesced: 16 samples x 64B contiguous per i
    }
  }
}

extern "C" void kernel_launch(void* const* d_in, const int* in_sizes, int n_in,
                              void* d_out, int out_size, void* d_ws, size_t ws_size,
                              hipStream_t stream) {
  (void)in_sizes; (void)n_in; (void)out_size; (void)ws_size;
  const float* x    = (const float*)d_in[0];
  const float* W0   = (const float*)d_in[1];
  const float* W1   = (const float*)d_in[2];
  const float* W2   = (const float*)d_in[3];
  const float* W3   = (const float*)d_in[4];
  const float* W4   = (const float*)d_in[5];
  const float* W5   = (const float*)d_in[6];
  const float* bias = (const float*)d_in[7];
  bf16x8* ws = (bf16x8*)d_ws;   // needs 151552 B

  prep_weights<<<(WTOT + 255) / 256, 256, 0, stream>>>(W0, W1, W2, W3, W4, W5, ws);
  mlp_kernel<<<NBLK, 512, 0, stream>>>(x, bias, (const bf16x8*)ws, (float*)d_out);
}

// Round 8
// 642.874 us; speedup vs baseline: 1.0068x; 1.0068x over previous
//
#include <hip/hip_runtime.h>
#include <stdint.h>

// MLP_tcnn: x(524288x64) -> [W0 64x128 relu] -> [W1..W4 128x128 relu] -> [W5 128x16] + bias
// R8 = R7 with the spill fixed.  R7's TPW-loop got unrolled+cross-scheduled by the
// compiler (tile-1 x-loads hoisted into tile-0 compute) -> peak pressure > 256-reg
// budget -> scratch thrash (WRITE 632MB).  Fix: #pragma unroll 1 on the tile loop
// (pins pressure to R6's verified 248<=256) + wave-uniform wid/sbase forced to SGPRs.
// Structure unchanged: whole 148KB frag-linear weight image staged to LDS once,
// static-offset conflict-free ds_read_b128 A-feed, lane-local kappa B (no LDS for
// activations, no main-loop barriers), 512-thr blocks, 2 waves/SIMD.

typedef __bf16 bf16x8 __attribute__((ext_vector_type(8)));
typedef float  floatx4 __attribute__((ext_vector_type(4)));

#define GAS __attribute__((address_space(1)))
#define LAS __attribute__((address_space(3)))

constexpr int NS   = 524288;        // samples
constexpr int SPW  = 64;            // samples per wave-tile
constexpr int NBLK = 512;           // blocks (8 waves each)
constexpr int TPW  = NS / (NBLK * 8 * SPW);   // = 2 tiles per wave

// weight image in 16B chunks inside d_ws, FRAG-LINEAR (frag = rb*KT + kt; 64 lanes x 16B):
// A-frag lane l, elem e = W[in = kappa(32kt+8*(l>>4)+e)][out = 16rb+(l&15)]
// L0 (K=64, kappa=identity on input): 8rb x 2kt = 16 frags; L1-4: 8 x 4 = 32; L5: 1 x 4.
constexpr int WTOT = 9472;          // total chunks = 151552 bytes

__device__ __host__ __forceinline__ int kappa(int s) {
  // s = 32*kt + 8*g + e  ->  feature 32*kt + 16*((e>>2)) + 4*g + (e&3)
  return 32 * (s >> 5) + 16 * ((s >> 2) & 1) + 4 * ((s >> 3) & 3) + (s & 3);
}

__global__ void prep_weights(const float* __restrict__ W0, const float* __restrict__ W1,
                             const float* __restrict__ W2, const float* __restrict__ W3,
                             const float* __restrict__ W4, const float* __restrict__ W5,
                             bf16x8* __restrict__ ws) {
  int gid = blockIdx.x * blockDim.x + threadIdx.x;
  if (gid >= WTOT) return;
  const float* Wsrc; int nout, kt_n, base, ident;
  if (gid < 1024)      { Wsrc = W0; nout = 128; kt_n = 2; base = 0;    ident = 1; }
  else if (gid < 3072) { Wsrc = W1; nout = 128; kt_n = 4; base = 1024; ident = 0; }
  else if (gid < 5120) { Wsrc = W2; nout = 128; kt_n = 4; base = 3072; ident = 0; }
  else if (gid < 7168) { Wsrc = W3; nout = 128; kt_n = 4; base = 5120; ident = 0; }
  else if (gid < 9216) { Wsrc = W4; nout = 128; kt_n = 4; base = 7168; ident = 0; }
  else                 { Wsrc = W5; nout = 16;  kt_n = 4; base = 9216; ident = 0; }
  int id   = gid - base;
  int lane = id & 63;
  int frag = id >> 6;
  int kt   = frag % kt_n;
  int rb   = frag / kt_n;
  int outf = rb * 16 + (lane & 15);
  int gg   = lane >> 4;
  bf16x8 v;
#pragma unroll
  for (int e = 0; e < 8; ++e) {
    int s  = 32 * kt + 8 * gg + e;           // k-slot
    int in = ident ? s : kappa(s);           // logical input feature at this slot
    v[e] = (__bf16)Wsrc[in * nout + outf];
  }
  ws[gid] = v;
}

__device__ __forceinline__ void zero_acc(floatx4 acc[8][4]) {
  floatx4 z = {0.f, 0.f, 0.f, 0.f};
#pragma unroll
  for (int ot = 0; ot < 8; ++ot)
#pragma unroll
    for (int i = 0; i < 4; ++i) acc[ot][i] = z;
}

// acc (C layout) -> B-frags for the next layer under kappa: pure lane-local relu+pack.
__device__ __forceinline__ void pack_relu(const floatx4 acc[8][4], bf16x8 B[4][4]) {
#pragma unroll
  for (int kt = 0; kt < 4; ++kt)
#pragma unroll
    for (int i = 0; i < 4; ++i) {
      floatx4 u = acc[2 * kt][i], v = acc[2 * kt + 1][i];
      bf16x8 b;
      b[0] = (__bf16)fmaxf(u[0], 0.f); b[1] = (__bf16)fmaxf(u[1], 0.f);
      b[2] = (__bf16)fmaxf(u[2], 0.f); b[3] = (__bf16)fmaxf(u[3], 0.f);
      b[4] = (__bf16)fmaxf(v[0], 0.f); b[5] = (__bf16)fmaxf(v[1], 0.f);
      b[6] = (__bf16)fmaxf(v[2], 0.f); b[7] = (__bf16)fmaxf(v[3], 0.f);
      B[kt][i] = b;
    }
}

__global__ void __launch_bounds__(512, 2) mlp_kernel(const float* __restrict__ x,
                                                     const float* __restrict__ bias,
                                                     const bf16x8* __restrict__ wimg,
                                                     float* __restrict__ out) {
  __shared__ bf16x8 Wlds[WTOT];        // 151552 B: entire frag-linear weight image

  const int t    = threadIdx.x;
  const int lane = t & 63;
  const int l15  = lane & 15;
  const int g    = lane >> 4;
  // wave index: wave-uniform -> force to SGPR so loop state costs no VGPRs
  const int w    = __builtin_amdgcn_readfirstlane(t >> 6);     // 0..7

  // ---- stage all weights -> LDS (once). Identity copy: per-wave 64-chunk slabs. ----
#pragma unroll
  for (int r = 0; r < 19; ++r) {
    int base = r * 512 + w * 64;
    if (base < WTOT)
      __builtin_amdgcn_global_load_lds((const GAS void*)(wimg + base + lane),
                                       (LAS void*)(Wlds + base), 16, 0, 0);
  }
  __syncthreads();   // drains vmcnt; only barrier in the kernel

  const int wid = __builtin_amdgcn_readfirstlane(blockIdx.x * 8 + w);  // 0..4095

#pragma unroll 1     // CRITICAL: no cross-tile scheduling -> keeps pressure at R6's level
  for (int k = 0; k < TPW; ++k) {
    const size_t sbase = ((size_t)wid * TPW + k) * SPW;   // wave-uniform (SGPR)

    bf16x8  B[4][4];     // B-frags: [kt][i], sample 16i+l15, k-slots 8g..8g+7 of chunk kt
    floatx4 acc[8][4];   // C: out-feature 16ot+4g+j, sample 16i+l15

    // ---- load x tile directly into B-frag layout (natural feature order) ----
    const float* xw = x + sbase * 64;
#pragma unroll
    for (int kt = 0; kt < 2; ++kt)
#pragma unroll
      for (int i = 0; i < 4; ++i) {
        const floatx4* p = (const floatx4*)(xw + (16 * i + l15) * 64 + 32 * kt + 8 * g);
        floatx4 lo = p[0], hi = p[1];
        bf16x8 v;
        v[0] = (__bf16)lo[0]; v[1] = (__bf16)lo[1]; v[2] = (__bf16)lo[2]; v[3] = (__bf16)lo[3];
        v[4] = (__bf16)hi[0]; v[5] = (__bf16)hi[1]; v[6] = (__bf16)hi[2]; v[7] = (__bf16)hi[3];
        B[kt][i] = v;
      }

    // ---- layer 0: K=64 ----
    zero_acc(acc);
#pragma unroll
    for (int kt = 0; kt < 2; ++kt)
#pragma unroll
      for (int ot = 0; ot < 8; ++ot) {
        bf16x8 a = Wlds[(ot * 2 + kt) * 64 + lane];       // ds_read_b128, static offset
#pragma unroll
        for (int i = 0; i < 4; ++i)
          acc[ot][i] = __builtin_amdgcn_mfma_f32_16x16x32_bf16(a, B[kt][i], acc[ot][i], 0, 0, 0);
      }

    // ---- layers 1..4: K=128, fully in-register ----
    constexpr int WOFFH[4] = {1024, 3072, 5120, 7168};
#pragma unroll
    for (int l = 0; l < 4; ++l) {
      pack_relu(acc, B);
      zero_acc(acc);
      const bf16x8* Wl = Wlds + WOFFH[l];
#pragma unroll
      for (int kt = 0; kt < 4; ++kt)
#pragma unroll
        for (int ot = 0; ot < 8; ++ot) {
          bf16x8 a = Wl[(ot * 4 + kt) * 64 + lane];
#pragma unroll
          for (int i = 0; i < 4; ++i)
            acc[ot][i] = __builtin_amdgcn_mfma_f32_16x16x32_bf16(a, B[kt][i], acc[ot][i], 0, 0, 0);
        }
    }

    // ---- layer 5: M=16, K=128, no relu, + bias, fp32 store ----
    pack_relu(acc, B);
    floatx4 o[4];
    {
      floatx4 z = {0.f, 0.f, 0.f, 0.f};
      o[0] = z; o[1] = z; o[2] = z; o[3] = z;
    }
#pragma unroll
    for (int kt = 0; kt < 4; ++kt) {
      bf16x8 a = Wlds[9216 + kt * 64 + lane];
#pragma unroll
      for (int i = 0; i < 4; ++i)
        o[i] = __builtin_amdgcn_mfma_f32_16x16x32_bf16(a, B[kt][i], o[i], 0, 0, 0);
    }
    floatx4 bv = *(const floatx4*)(bias + 4 * g);
    floatx4* outv = (floatx4*)out;
#pragma unroll
    for (int i = 0; i < 4; ++i) {
      size_t s = sbase + 16 * i + l15;
      outv[s * 4 + g] = o[i] + bv;    // coalesced: 16 samples x 64B contiguous per i
    }
  }
}

extern "C" void kernel_launch(void* const* d_in, const int* in_sizes, int n_in,
                              void* d_out, int out_size, void* d_ws, size_t ws_size,
                              hipStream_t stream) {
  (void)in_sizes; (void)n_in; (void)out_size; (void)ws_size;
  const float* x    = (const float*)d_in[0];
  const float* W0   = (const float*)d_in[1];
  const float* W1   = (const float*)d_in[2];
  const float* W2   = (const float*)d_in[3];
  const float* W3   = (const float*)d_in[4];
  const float* W4   = (const float*)d_in[5];
  const float* W5   = (const float*)d_in[6];
  const float* bias = (const float*)d_in[7];
  bf16x8* ws = (bf16x8*)d_ws;   // needs 151552 B

  prep_weights<<<(WTOT + 255) / 256, 256, 0, stream>>>(W0, W1, W2, W3, W4, W5, ws);
  mlp_kernel<<<NBLK, 512, 0, stream>>>(x, bias, (const bf16x8*)ws, (float*)d_out);
}

// Round 9
// 254.071 us; speedup vs baseline: 2.5475x; 2.5303x over previous
//
#include <hip/hip_runtime.h>
#include <stdint.h>

// MLP_tcnn: x(524288x64) -> [W0 64x128 relu] -> [W1..W4 128x128 relu] -> [W5 128x16] + bias
// R9: kill the LICM spill. R7/R8's A-frag ds_reads were loop-invariant across the tile
// loop -> MachineLICM hoisted all 148 frags (592 VGPRs) out of the loop -> 2.3KB/thread
// scratch (WRITE 628MB, FETCH 664MB). unroll-1 doesn't inhibit LICM (R8 == R7 proved it).
// Fix: (a) NO tile loop - 1024 blocks, each wave does exactly one 64-sample tile
// (R6's verified-clean codegen shape); (b) sched_barrier(0) after each kt-group so the
// in-body scheduler can't batch more than 8 A-frags (32 regs) at once.
// Structure: whole 148KB frag-linear weight image in LDS (staged once per block),
// static-offset conflict-free ds_read_b128 A-feed, lane-local kappa B-frags, no
// main-loop barriers, 512-thr blocks, 2 waves/SIMD.

typedef __bf16 bf16x8 __attribute__((ext_vector_type(8)));
typedef float  floatx4 __attribute__((ext_vector_type(4)));

#define GAS __attribute__((address_space(1)))
#define LAS __attribute__((address_space(3)))

constexpr int NS   = 524288;        // samples
constexpr int SPW  = 64;            // samples per wave-tile
constexpr int NBLK = NS / (8 * SPW);   // 1024 blocks, 8 waves each, ONE tile per wave

// weight image in 16B chunks inside d_ws, FRAG-LINEAR (frag = rb*KT + kt; 64 lanes x 16B):
// A-frag lane l, elem e = W[in = kappa(32kt+8*(l>>4)+e)][out = 16rb+(l&15)]
// L0 (K=64, kappa=identity on input): 8rb x 2kt = 16 frags; L1-4: 8 x 4 = 32; L5: 1 x 4.
constexpr int WTOT = 9472;          // total chunks = 151552 bytes

__device__ __host__ __forceinline__ int kappa(int s) {
  // s = 32*kt + 8*g + e  ->  feature 32*kt + 16*((e>>2)) + 4*g + (e&3)
  return 32 * (s >> 5) + 16 * ((s >> 2) & 1) + 4 * ((s >> 3) & 3) + (s & 3);
}

__global__ void prep_weights(const float* __restrict__ W0, const float* __restrict__ W1,
                             const float* __restrict__ W2, const float* __restrict__ W3,
                             const float* __restrict__ W4, const float* __restrict__ W5,
                             bf16x8* __restrict__ ws) {
  int gid = blockIdx.x * blockDim.x + threadIdx.x;
  if (gid >= WTOT) return;
  const float* Wsrc; int nout, kt_n, base, ident;
  if (gid < 1024)      { Wsrc = W0; nout = 128; kt_n = 2; base = 0;    ident = 1; }
  else if (gid < 3072) { Wsrc = W1; nout = 128; kt_n = 4; base = 1024; ident = 0; }
  else if (gid < 5120) { Wsrc = W2; nout = 128; kt_n = 4; base = 3072; ident = 0; }
  else if (gid < 7168) { Wsrc = W3; nout = 128; kt_n = 4; base = 5120; ident = 0; }
  else if (gid < 9216) { Wsrc = W4; nout = 128; kt_n = 4; base = 7168; ident = 0; }
  else                 { Wsrc = W5; nout = 16;  kt_n = 4; base = 9216; ident = 0; }
  int id   = gid - base;
  int lane = id & 63;
  int frag = id >> 6;
  int kt   = frag % kt_n;
  int rb   = frag / kt_n;
  int outf = rb * 16 + (lane & 15);
  int gg   = lane >> 4;
  bf16x8 v;
#pragma unroll
  for (int e = 0; e < 8; ++e) {
    int s  = 32 * kt + 8 * gg + e;           // k-slot
    int in = ident ? s : kappa(s);           // logical input feature at this slot
    v[e] = (__bf16)Wsrc[in * nout + outf];
  }
  ws[gid] = v;
}

__device__ __forceinline__ void zero_acc(floatx4 acc[8][4]) {
  floatx4 z = {0.f, 0.f, 0.f, 0.f};
#pragma unroll
  for (int ot = 0; ot < 8; ++ot)
#pragma unroll
    for (int i = 0; i < 4; ++i) acc[ot][i] = z;
}

// acc (C layout) -> B-frags for the next layer under kappa: pure lane-local relu+pack.
__device__ __forceinline__ void pack_relu(const floatx4 acc[8][4], bf16x8 B[4][4]) {
#pragma unroll
  for (int kt = 0; kt < 4; ++kt)
#pragma unroll
    for (int i = 0; i < 4; ++i) {
      floatx4 u = acc[2 * kt][i], v = acc[2 * kt + 1][i];
      bf16x8 b;
      b[0] = (__bf16)fmaxf(u[0], 0.f); b[1] = (__bf16)fmaxf(u[1], 0.f);
      b[2] = (__bf16)fmaxf(u[2], 0.f); b[3] = (__bf16)fmaxf(u[3], 0.f);
      b[4] = (__bf16)fmaxf(v[0], 0.f); b[5] = (__bf16)fmaxf(v[1], 0.f);
      b[6] = (__bf16)fmaxf(v[2], 0.f); b[7] = (__bf16)fmaxf(v[3], 0.f);
      B[kt][i] = b;
    }
}

__global__ void __launch_bounds__(512, 2) mlp_kernel(const float* __restrict__ x,
                                                     const float* __restrict__ bias,
                                                     const bf16x8* __restrict__ wimg,
                                                     float* __restrict__ out) {
  __shared__ bf16x8 Wlds[WTOT];        // 151552 B: entire frag-linear weight image

  const int t    = threadIdx.x;
  const int lane = t & 63;
  const int l15  = lane & 15;
  const int g    = lane >> 4;
  const int w    = __builtin_amdgcn_readfirstlane(t >> 6);     // wave 0..7 (SGPR)

  // ---- stage all weights -> LDS (once). Identity copy: per-wave 64-chunk slabs. ----
#pragma unroll
  for (int r = 0; r < 19; ++r) {
    int base = r * 512 + w * 64;
    if (base < WTOT)
      __builtin_amdgcn_global_load_lds((const GAS void*)(wimg + base + lane),
                                       (LAS void*)(Wlds + base), 16, 0, 0);
  }
  __syncthreads();   // drains vmcnt; only barrier in the kernel

  const int wid = __builtin_amdgcn_readfirstlane(blockIdx.x * 8 + w);  // 0..8191
  const size_t sbase = (size_t)wid * SPW;    // this wave's 64 samples (SGPR)

  bf16x8  B[4][4];     // B-frags: [kt][i], sample 16i+l15, k-slots 8g..8g+7 of chunk kt
  floatx4 acc[8][4];   // C: out-feature 16ot+4g+j, sample 16i+l15

  // ---- load x tile directly into B-frag layout (natural feature order) ----
  const float* xw = x + sbase * 64;
#pragma unroll
  for (int kt = 0; kt < 2; ++kt)
#pragma unroll
    for (int i = 0; i < 4; ++i) {
      const floatx4* p = (const floatx4*)(xw + (16 * i + l15) * 64 + 32 * kt + 8 * g);
      floatx4 lo = p[0], hi = p[1];
      bf16x8 v;
      v[0] = (__bf16)lo[0]; v[1] = (__bf16)lo[1]; v[2] = (__bf16)lo[2]; v[3] = (__bf16)lo[3];
      v[4] = (__bf16)hi[0]; v[5] = (__bf16)hi[1]; v[6] = (__bf16)hi[2]; v[7] = (__bf16)hi[3];
      B[kt][i] = v;
    }

  // ---- layer 0: K=64 ----
  zero_acc(acc);
#pragma unroll
  for (int kt = 0; kt < 2; ++kt) {
    bf16x8 a[8];
#pragma unroll
    for (int ot = 0; ot < 8; ++ot)
      a[ot] = Wlds[(ot * 2 + kt) * 64 + lane];            // 8x ds_read_b128, static offs
#pragma unroll
    for (int ot = 0; ot < 8; ++ot)
#pragma unroll
      for (int i = 0; i < 4; ++i)
        acc[ot][i] = __builtin_amdgcn_mfma_f32_16x16x32_bf16(a[ot], B[kt][i], acc[ot][i], 0, 0, 0);
    __builtin_amdgcn_sched_barrier(0);   // cap A-batch at 8 frags (32 VGPRs)
  }

  // ---- layers 1..4: K=128, fully in-register ----
  constexpr int WOFFH[4] = {1024, 3072, 5120, 7168};
#pragma unroll
  for (int l = 0; l < 4; ++l) {
    pack_relu(acc, B);
    zero_acc(acc);
    const bf16x8* Wl = Wlds + WOFFH[l];
#pragma unroll
    for (int kt = 0; kt < 4; ++kt) {
      bf16x8 a[8];
#pragma unroll
      for (int ot = 0; ot < 8; ++ot)
        a[ot] = Wl[(ot * 4 + kt) * 64 + lane];
#pragma unroll
      for (int ot = 0; ot < 8; ++ot)
#pragma unroll
        for (int i = 0; i < 4; ++i)
          acc[ot][i] = __builtin_amdgcn_mfma_f32_16x16x32_bf16(a[ot], B[kt][i], acc[ot][i], 0, 0, 0);
      __builtin_amdgcn_sched_barrier(0);
    }
  }

  // ---- layer 5: M=16, K=128, no relu, + bias, fp32 store ----
  pack_relu(acc, B);
  floatx4 o[4];
  {
    floatx4 z = {0.f, 0.f, 0.f, 0.f};
    o[0] = z; o[1] = z; o[2] = z; o[3] = z;
  }
#pragma unroll
  for (int kt = 0; kt < 4; ++kt) {
    bf16x8 a = Wlds[9216 + kt * 64 + lane];
#pragma unroll
    for (int i = 0; i < 4; ++i)
      o[i] = __builtin_amdgcn_mfma_f32_16x16x32_bf16(a, B[kt][i], o[i], 0, 0, 0);
  }
  floatx4 bv = *(const floatx4*)(bias + 4 * g);
  floatx4* outv = (floatx4*)out;
#pragma unroll
  for (int i = 0; i < 4; ++i) {
    size_t s = sbase + 16 * i + l15;
    outv[s * 4 + g] = o[i] + bv;    // coalesced: 16 samples x 64B contiguous per i
  }
}

extern "C" void kernel_launch(void* const* d_in, const int* in_sizes, int n_in,
                              void* d_out, int out_size, void* d_ws, size_t ws_size,
                              hipStream_t stream) {
  (void)in_sizes; (void)n_in; (void)out_size; (void)ws_size;
  const float* x    = (const float*)d_in[0];
  const float* W0   = (const float*)d_in[1];
  const float* W1   = (const float*)d_in[2];
  const float* W2   = (const float*)d_in[3];
  const float* W3   = (const float*)d_in[4];
  const float* W4   = (const float*)d_in[5];
  const float* W5   = (const float*)d_in[6];
  const float* bias = (const float*)d_in[7];
  bf16x8* ws = (bf16x8*)d_ws;   // needs 151552 B

  prep_weights<<<(WTOT + 255) / 256, 256, 0, stream>>>(W0, W1, W2, W3, W4, W5, ws);
  mlp_kernel<<<NBLK, 512, 0, stream>>>(x, bias, (const bf16x8*)ws, (float*)d_out);
}